// Round 1
// baseline (46.996 us; speedup 1.0000x reference)
//
#include <hip/hip_runtime.h>

// Problem geometry (fixed by the reference):
//   x : (1,24,56,56) f32      -> c*3136 + h*56 + w
//   w1: (96,3,21)    f32      -> i*63 + j*21 + k
//   w2: (12,7,21)    f32      -> c*147 + j*21 + k
//   y : (1,96,56,56) f32      -> i*3136 + h*56 + w
//
// y[i,h,w] = sum_{j<3,k<21} t5[h+j-1,w,k] * w1[i,j,k]
// t5[h,w,k] = sum_{c<12,jj<7} t3r[c,h,w+jj-3] * w2[c,jj,k]
// t3r[c,h,w] = x[c,h,(w-1)%56] + x[c+12,h,(w-1)%56]

#define NH 56
#define NW 56
#define NC 12
#define NK 21
#define NI 96

__global__ __launch_bounds__(256)
void fused_rows_kernel(const float* __restrict__ x,
                       const float* __restrict__ w1,
                       const float* __restrict__ w2,
                       float* __restrict__ y) {
    __shared__ float s_t3[3][NC][NW];        // rolled+summed input rows h-1..h+1  (8 KB)
    __shared__ float s_t5[3][NW][NK];        // t5 rows h-1..h+1                   (14 KB)
    __shared__ float s_w2[NC * 7 * NK];      // 7 KB
    __shared__ float s_w1[NI * 3 * NK];      // 24 KB

    const int h   = blockIdx.x;
    const int tid = threadIdx.x;

    // --- stage weights into LDS ---
    for (int e = tid; e < NC * 7 * NK; e += 256) s_w2[e] = w2[e];
    for (int e = tid; e < NI * 3 * NK; e += 256) s_w1[e] = w1[e];

    // --- stage t3 (channel-pair sum + width roll) for rows h-1..h+1 ---
    for (int e = tid; e < 3 * NC * NW; e += 256) {
        const int r = e / (NC * NW);
        const int c = (e / NW) % NC;
        const int w = e % NW;
        const int hh = h - 1 + r;
        float v = 0.0f;
        if (hh >= 0 && hh < NH) {
            const int wsrc = (w + NW - 1) % NW;     // roll(+1): out[w] = in[w-1]
            const int base = hh * NW + wsrc;
            v = x[c * 3136 + base] + x[(c + 12) * 3136 + base];
        }
        s_t3[r][c][w] = v;
    }
    __syncthreads();

    // --- stage 1: t5[r][w][k] = sum_{c,jj} t3[r][c][w+jj-3] * w2[c,jj,k] ---
    for (int e = tid; e < 3 * NW * NK; e += 256) {
        const int r = e / (NW * NK);
        const int w = (e / NK) % NW;
        const int k = e % NK;
        float acc = 0.0f;
        #pragma unroll
        for (int jj = 0; jj < 7; ++jj) {
            const int ww = w + jj - 3;
            if (ww < 0 || ww >= NW) continue;       // zero width-pad
            #pragma unroll
            for (int c = 0; c < NC; ++c) {
                acc += s_t3[r][c][ww] * s_w2[c * 147 + jj * NK + k];
            }
        }
        s_t5[r][w][k] = acc;
    }
    __syncthreads();

    // --- stage 2: y[i,h,w] = sum_{j,k} t5[j][w][k] * w1[i,j,k] ---
    for (int e = tid; e < NI * NW; e += 256) {
        const int i = e / NW;
        const int w = e % NW;
        float acc = 0.0f;
        #pragma unroll
        for (int j = 0; j < 3; ++j) {
            const float* __restrict__ wrow = &s_w1[i * 63 + j * NK];
            const float* __restrict__ trow = &s_t5[j][w][0];
            #pragma unroll
            for (int k = 0; k < NK; ++k) acc += trow[k] * wrow[k];
        }
        y[i * 3136 + h * NW + w] = acc;
    }
}

extern "C" void kernel_launch(void* const* d_in, const int* in_sizes, int n_in,
                              void* d_out, int out_size, void* d_ws, size_t ws_size,
                              hipStream_t stream) {
    const float* x  = (const float*)d_in[0];
    const float* w1 = (const float*)d_in[1];
    const float* w2 = (const float*)d_in[2];
    float* y = (float*)d_out;
    fused_rows_kernel<<<dim3(NH), dim3(256), 0, stream>>>(x, w1, w2, y);
}

// Round 2
// 21.797 us; speedup vs baseline: 2.1561x; 2.1561x over previous
//
#include <hip/hip_runtime.h>

// Geometry:
//   x : (1,24,56,56) f32   -> c*3136 + h*56 + w
//   w1: (96,3,21)    f32   -> i*63 + j*21 + k
//   w2: (12,7,21)    f32   -> c*147 + jj*21 + k
//   y : (1,96,56,56) f32   -> i*3136 + h*56 + w
//   t5: (56,56,21)   f32 workspace -> (h*56+w)*21 + k
//
// t3r[c,h,w] = x[c,h,(w-1)%56] + x[c+12,h,(w-1)%56]        (roll +1 on width)
// t5[h,w,k]  = sum_{c<12,jj<7} t3r[c,h,w+jj-3] * w2[c,jj,k] (zero width-pad)
// y[i,h,w]   = sum_{j<3,k<21}  t5[h+j-1,w,k]  * w1[i,j,k]   (zero height-pad)

#define NH 56
#define NW 56
#define NC 12
#define NK 21
#define NI 96
#define WCHUNK 14   // 4 chunks of 14 along width
#define ICHUNK 16   // 6 chunks of 16 along output channels

__global__ __launch_bounds__(256)
void t5_kernel(const float* __restrict__ x,
               const float* __restrict__ w2,
               float* __restrict__ t5) {
    __shared__ float s_w2[NC * 7 * NK];          // 1764 f32, 7 KB
    __shared__ float s_t3[NC][WCHUNK + 6];       // 12 x 20

    const int h   = blockIdx.x;
    const int w0  = blockIdx.y * WCHUNK;
    const int tid = threadIdx.x;

    for (int e = tid; e < NC * 7 * NK; e += 256) s_w2[e] = w2[e];

    // stage t3 slice: p = 0..19 <-> ww = w0-3+p  (zero outside [0,56))
    for (int e = tid; e < NC * (WCHUNK + 6); e += 256) {
        const int c = e / (WCHUNK + 6);
        const int p = e % (WCHUNK + 6);
        const int ww = w0 - 3 + p;
        float v = 0.0f;
        if (ww >= 0 && ww < NW) {
            const int wsrc = (ww + NW - 1) % NW;   // roll(+1): out[w] = in[w-1]
            const int base = h * NW + wsrc;
            v = x[c * 3136 + base] + x[(c + 12) * 3136 + base];
        }
        s_t3[c][p] = v;
    }
    __syncthreads();

    // 294 outputs per block
    for (int e = tid; e < WCHUNK * NK; e += 256) {
        const int wl = e / NK;                    // local w
        const int k  = e % NK;
        float acc = 0.0f;
        #pragma unroll
        for (int jj = 0; jj < 7; ++jj) {
            #pragma unroll
            for (int c = 0; c < NC; ++c) {
                acc += s_t3[c][wl + jj] * s_w2[c * 147 + jj * NK + k];
            }
        }
        t5[(h * NW + w0 + wl) * NK + k] = acc;
    }
}

__global__ __launch_bounds__(256)
void y_kernel(const float* __restrict__ t5,
              const float* __restrict__ w1,
              float* __restrict__ y) {
    __shared__ float s_t5[3][NW * NK];           // 3 rows, 14 KB
    __shared__ float s_w1[ICHUNK * 63];          // 4 KB

    const int h   = blockIdx.x;
    const int i0  = blockIdx.y * ICHUNK;
    const int tid = threadIdx.x;

    for (int e = tid; e < ICHUNK * 63; e += 256) s_w1[e] = w1[i0 * 63 + e];

    for (int e = tid; e < 3 * NW * NK; e += 256) {
        const int j = e / (NW * NK);
        const int r = e % (NW * NK);
        const int hh = h - 1 + j;
        s_t5[j][r] = (hh >= 0 && hh < NH) ? t5[hh * (NW * NK) + r] : 0.0f;
    }
    __syncthreads();

    // 896 outputs per block
    for (int e = tid; e < ICHUNK * NW; e += 256) {
        const int il = e / NW;
        const int w  = e % NW;
        float acc = 0.0f;
        #pragma unroll
        for (int j = 0; j < 3; ++j) {
            const float* __restrict__ tp = &s_t5[j][w * NK];
            const float* __restrict__ wp = &s_w1[il * 63 + j * NK];
            #pragma unroll
            for (int k = 0; k < NK; ++k) acc += tp[k] * wp[k];
        }
        y[(i0 + il) * 3136 + h * NW + w] = acc;
    }
}

extern "C" void kernel_launch(void* const* d_in, const int* in_sizes, int n_in,
                              void* d_out, int out_size, void* d_ws, size_t ws_size,
                              hipStream_t stream) {
    const float* x  = (const float*)d_in[0];
    const float* w1 = (const float*)d_in[1];
    const float* w2 = (const float*)d_in[2];
    float* y  = (float*)d_out;
    float* t5 = (float*)d_ws;                    // 56*56*21*4 = 263 KB

    t5_kernel<<<dim3(NH, NW / WCHUNK), dim3(256), 0, stream>>>(x, w2, t5);
    y_kernel <<<dim3(NH, NI / ICHUNK), dim3(256), 0, stream>>>(t5, w1, y);
}